// Round 9
// baseline (78.690 us; speedup 1.0000x reference)
//
#include <hip/hip_runtime.h>

#define L 512
#define D 768
#define LOG2E  1.44269504088896341f
#define LOG2E2 2.88539008177792681f   // 2*log2(e)

typedef __attribute__((ext_vector_type(8))) short bf16x8;
typedef __attribute__((ext_vector_type(4))) float f32x4;

__device__ __forceinline__ ushort f2bf(float f) {
    unsigned u = __builtin_bit_cast(unsigned, f);
    u += 0x7FFFu + ((u >> 16) & 1u);          // RNE
    return (ushort)(u >> 16);
}

// ---------------- prep: cast X->bf16 and build transposed bf16 copies ---------
// z: 0 = X (512x768; also writes straight cast), 1 = Wq, 2 = Wk, 3 = Wt (768x768)
__global__ __launch_bounds__(256) void transpose_cast(
    const float* __restrict__ X,  const float* __restrict__ Wq,
    const float* __restrict__ Wk, const float* __restrict__ Wt,
    ushort* __restrict__ Xbf, ushort* __restrict__ XbfT,
    ushort* __restrict__ WqT, ushort* __restrict__ WkT, ushort* __restrict__ WtT)
{
    __shared__ float tile[64][65];
    const int z = blockIdx.z;
    const float* src = z == 0 ? X : z == 1 ? Wq : z == 2 ? Wk : Wt;
    ushort* dstT     = z == 0 ? XbfT : z == 1 ? WqT : z == 2 ? WkT : WtT;
    const int R = (z == 0) ? L : D;
    const int r0 = blockIdx.y * 64, c0 = blockIdx.x * 64;
    if (r0 >= R) return;
    const int t = threadIdx.x;
    const int tr = t >> 4;           // 0..15
    const int tc = (t & 15) * 4;     // 0..60
    #pragma unroll
    for (int p = 0; p < 4; ++p) {
        int r = tr + p * 16;
        float4 v = *(const float4*)&src[(r0 + r) * D + c0 + tc];
        tile[r][tc + 0] = v.x; tile[r][tc + 1] = v.y;
        tile[r][tc + 2] = v.z; tile[r][tc + 3] = v.w;
        if (z == 0) {
            ushort4 b;
            b.x = f2bf(v.x); b.y = f2bf(v.y); b.z = f2bf(v.z); b.w = f2bf(v.w);
            *(ushort4*)&Xbf[(r0 + r) * D + c0 + tc] = b;
        }
    }
    __syncthreads();
    #pragma unroll
    for (int p = 0; p < 4; ++p) {
        int c = tr + p * 16;
        ushort4 b;
        b.x = f2bf(tile[tc + 0][c]);
        b.y = f2bf(tile[tc + 1][c]);
        b.z = f2bf(tile[tc + 2][c]);
        b.w = f2bf(tile[tc + 3][c]);
        *(ushort4*)&dstT[(c0 + c) * R + r0 + tc] = b;
    }
}

// ---------------- bf16 MFMA GEMM, 32x64 tile, BK=64, 4 waves ------------------
// MODE 0: QK fused (blockIdx.z: 0 -> Qb fp32 + Eq=exp2(c*Q); 1 -> EkT transposed)
// MODE 1: PV  (A=Pbf, Bt=XbfT, K=512, bf16 out Cb)
// MODE 2: OUT (A=Wbf, Bt=WtT, K=768, +bias +addend, fp32 out Cf)
template<int MODE>
__global__ __launch_bounds__(256) void gemm_mfma(
    const ushort* __restrict__ A,
    const ushort* __restrict__ Bt0, const ushort* __restrict__ Bt1,
    const float* __restrict__ bias0, const float* __restrict__ bias1,
    float* __restrict__ Qb, float* __restrict__ Eq, float* __restrict__ EkT,
    ushort* __restrict__ Cb, float* __restrict__ Cf,
    const float* __restrict__ addend, int K)
{
    const int N = D;
    const int bz = (MODE == 0) ? blockIdx.z : 0;
    const ushort* Bt   = bz ? Bt1 : Bt0;
    const float*  bias = bz ? bias1 : bias0;

    __shared__ ushort As[32][72];   // +8 pad
    __shared__ ushort Bs[64][72];

    const int m0 = blockIdx.y * 32;
    const int n0 = blockIdx.x * 64;
    const int t = threadIdx.x;
    const int l = t & 63, w = t >> 6;
    const int wr = w >> 1, wc = w & 1;
    const int frow = l & 15;
    const int kg = (l >> 4) * 8;

    const int srow = t >> 3;         // 0..31
    const int sk   = (t & 7) * 8;    // 0..56

    f32x4 acc[2] = {};

    for (int k0 = 0; k0 < K; k0 += 64) {
        uint4 a0 = *(const uint4*)&A [(m0 + srow)      * K + k0 + sk];
        uint4 b0 = *(const uint4*)&Bt[(n0 + srow)      * K + k0 + sk];
        uint4 b1 = *(const uint4*)&Bt[(n0 + srow + 32) * K + k0 + sk];
        if (k0) __syncthreads();
        *(uint4*)&As[srow][sk]      = a0;
        *(uint4*)&Bs[srow][sk]      = b0;
        *(uint4*)&Bs[srow + 32][sk] = b1;
        __syncthreads();

        bf16x8 af[2], bfr[2][2];
        #pragma unroll
        for (int kk = 0; kk < 2; ++kk) {
            af[kk] = *(const bf16x8*)&As[16 * wr + frow][32 * kk + kg];
            #pragma unroll
            for (int fc = 0; fc < 2; ++fc)
                bfr[fc][kk] = *(const bf16x8*)&Bs[32 * wc + 16 * fc + frow][32 * kk + kg];
        }
        #pragma unroll
        for (int fc = 0; fc < 2; ++fc) {
            acc[fc] = __builtin_amdgcn_mfma_f32_16x16x32_bf16(af[0], bfr[fc][0], acc[fc], 0, 0, 0);
            acc[fc] = __builtin_amdgcn_mfma_f32_16x16x32_bf16(af[1], bfr[fc][1], acc[fc], 0, 0, 0);
        }
    }

    const int rg = (l >> 4) * 4;
    #pragma unroll
    for (int fc = 0; fc < 2; ++fc) {
        const int col = n0 + 32 * wc + 16 * fc + frow;
        const int row0 = m0 + 16 * wr + rg;
        if (MODE == 0 && bz) {
            // EkT[col][row0..row0+3] = exp2(c*(acc+bias)) — one float4 store
            const float bv = bias[col];
            float4 e;
            e.x = __builtin_amdgcn_exp2f(LOG2E2 * (acc[fc][0] + bv));
            e.y = __builtin_amdgcn_exp2f(LOG2E2 * (acc[fc][1] + bv));
            e.z = __builtin_amdgcn_exp2f(LOG2E2 * (acc[fc][2] + bv));
            e.w = __builtin_amdgcn_exp2f(LOG2E2 * (acc[fc][3] + bv));
            *(float4*)&EkT[col * L + row0] = e;
        } else {
            const float bv = (MODE == 1) ? 0.f : bias[col];
            #pragma unroll
            for (int i = 0; i < 4; ++i) {
                const int row = row0 + i;
                float v = acc[fc][i] + bv;
                if (MODE == 0) {                 // z==0: Q path
                    Qb[row * N + col] = v;
                    Eq[row * N + col] = __builtin_amdgcn_exp2f(LOG2E2 * v);
                } else if (MODE == 1) {
                    Cb[row * N + col] = f2bf(v);
                } else {
                    Cf[row * N + col] = v + addend[row * N + col];
                }
            }
        }
    }
}

// ---------------- raw partial scores, lane = k, loop over d -------------------
// Grid (8 kt, 2 dh, 64 qg) x 256 threads (4 waves). Wave w handles q-pair
// (qg*4+w)*2, k = kt*64+lane, d in [dh*384, dh*384+384). No cross-lane ops;
// qe/w are wave-uniform (scalar) loads; EkT[d][k] loads coalesced, L1-shared
// across the block's 4 waves. Row-constant terms (Wsum, b_att) dropped:
// softmax is invariant to per-row constants. score_p = -2*sum w*rcp(qe*ek+1)
// (+ mask[k] on the dh==0 half).
__global__ __launch_bounds__(256) void score_k(
    const float* __restrict__ Eq, const float* __restrict__ EkT,
    const float* __restrict__ mask, const float* __restrict__ w_att,
    float* __restrict__ sP0, float* __restrict__ sP1)
{
    const int kt = blockIdx.x, dh = blockIdx.y, qg = blockIdx.z;
    const int lane = threadIdx.x & 63, w = threadIdx.x >> 6;
    const int q0 = (qg * 4 + w) * 2;
    const int k  = kt * 64 + lane;
    const int dbase = dh * 384;

    const float* __restrict__ eq0 = Eq + q0 * D + dbase;
    const float* __restrict__ eq1 = Eq + (q0 + 1) * D + dbase;
    const float* __restrict__ wa  = w_att + dbase;
    const float* __restrict__ ekp = EkT + dbase * L + k;

    float acc0 = 0.f, acc1 = 0.f;
    #pragma unroll 16
    for (int d = 0; d < 384; ++d) {
        float ek = ekp[d * L];
        float a  = eq0[d];
        float b  = eq1[d];
        float ww = wa[d];
        acc0 = fmaf(ww, __builtin_amdgcn_rcpf(fmaf(a, ek, 1.f)), acc0);
        acc1 = fmaf(ww, __builtin_amdgcn_rcpf(fmaf(b, ek, 1.f)), acc1);
    }
    const float mk = (dh == 0) ? mask[k] : 0.f;
    float* __restrict__ dst = dh ? sP1 : sP0;
    dst[q0 * L + k]       = fmaf(-2.f, acc0, mk);
    dst[(q0 + 1) * L + k] = fmaf(-2.f, acc1, mk);
}

// ---------------- softmax (sum of d-half partials) -> bf16 probs --------------
__global__ __launch_bounds__(512) void softmax_probs(
    const float* __restrict__ sP0, const float* __restrict__ sP1,
    ushort* __restrict__ Pbf)
{
    __shared__ float redA[8], redB[8], redC[8], redD[8];
    const int q0 = blockIdx.x * 2;
    const int tid = threadIdx.x;
    const int lane = tid & 63, wave = tid >> 6;

    float v0 = sP0[q0 * L + tid]       + sP1[q0 * L + tid];
    float v1 = sP0[(q0 + 1) * L + tid] + sP1[(q0 + 1) * L + tid];

    float m0 = v0, m1 = v1;
    #pragma unroll
    for (int off = 32; off; off >>= 1) {
        m0 = fmaxf(m0, __shfl_xor(m0, off));
        m1 = fmaxf(m1, __shfl_xor(m1, off));
    }
    if (lane == 0) { redA[wave] = m0; redB[wave] = m1; }
    __syncthreads();
    float mm0 = redA[0], mm1 = redB[0];
    #pragma unroll
    for (int i = 1; i < 8; ++i) { mm0 = fmaxf(mm0, redA[i]); mm1 = fmaxf(mm1, redB[i]); }
    float e0 = __builtin_amdgcn_exp2f(LOG2E * (v0 - mm0));
    float e1 = __builtin_amdgcn_exp2f(LOG2E * (v1 - mm1));
    float s0 = e0, s1 = e1;
    #pragma unroll
    for (int off = 32; off; off >>= 1) {
        s0 += __shfl_xor(s0, off);
        s1 += __shfl_xor(s1, off);
    }
    if (lane == 0) { redC[wave] = s0; redD[wave] = s1; }
    __syncthreads();
    float t0 = redC[0], t1 = redD[0];
    #pragma unroll
    for (int i = 1; i < 8; ++i) { t0 += redC[i]; t1 += redD[i]; }
    Pbf[q0 * L + tid]       = f2bf(e0 * __builtin_amdgcn_rcpf(t0));
    Pbf[(q0 + 1) * L + tid] = f2bf(e1 * __builtin_amdgcn_rcpf(t1));
}

extern "C" void kernel_launch(void* const* d_in, const int* in_sizes, int n_in,
                              void* d_out, int out_size, void* d_ws, size_t ws_size,
                              hipStream_t stream) {
    const float* X     = (const float*)d_in[0];
    const float* mask  = (const float*)d_in[1];
    const float* Wq    = (const float*)d_in[2];
    const float* bq    = (const float*)d_in[3];
    const float* Wk    = (const float*)d_in[4];
    const float* bk    = (const float*)d_in[5];
    const float* w_att = (const float*)d_in[6];
    // d_in[7] = b_att: row-constant in the softmax -> provably no effect; dropped.
    const float* Wt    = (const float*)d_in[8];
    const float* bt    = (const float*)d_in[9];
    float* out = (float*)d_out;

    const int LD = L * D, DD = D * D, LL = L * L;
    float*  Qb   = (float*)d_ws;          // [L*D] fp32 Q (final addend)
    float*  Eq   = Qb + LD;               // [L*D] exp2(c*Q)
    float*  EkT  = Eq + LD;               // [D][L] exp2(c*K) transposed
    float*  sP0  = EkT + LD;              // [L][L] partial scores d-half 0 (+mask)
    float*  sP1  = sP0 + LL;              // [L][L] partial scores d-half 1
    ushort* Xbf  = (ushort*)(sP1 + LL);   // [L*D] bf16 X
    ushort* XbfT = Xbf + LD;              // [D][L] bf16 X^T
    ushort* WqT  = XbfT + LD;             // [D][D]
    ushort* WkT  = WqT + DD;
    ushort* WtT  = WkT + DD;
    ushort* Pbf  = WtT + DD;              // [L][L] bf16 probs
    ushort* Wbf  = Pbf + LL;              // [L][D] bf16 weighted

    // prep: bf16 casts + transposes
    transpose_cast<<<dim3(D / 64, D / 64, 4), 256, 0, stream>>>(
        X, Wq, Wk, Wt, Xbf, XbfT, WqT, WkT, WtT);

    // z=0: Qb + Eq ; z=1: EkT (transposed, exp'd)
    gemm_mfma<0><<<dim3(D / 64, L / 32, 2), 256, 0, stream>>>(
        Xbf, WqT, WkT, bq, bk, Qb, Eq, EkT, nullptr, nullptr, nullptr, D);

    // partial scores, lane = k
    score_k<<<dim3(8, 2, 64), 256, 0, stream>>>(Eq, EkT, mask, w_att, sP0, sP1);

    // softmax over partial sums -> bf16 probs
    softmax_probs<<<dim3(L / 2), 512, 0, stream>>>(sP0, sP1, Pbf);

    // weighted = probs @ X  (bf16 out)
    gemm_mfma<1><<<dim3(D / 64, L / 32, 1), 256, 0, stream>>>(
        Pbf, XbfT, nullptr, nullptr, nullptr, nullptr, nullptr, nullptr, Wbf, nullptr, nullptr, L);

    // out = weighted@Wt + bt + Q  (fp32)
    gemm_mfma<2><<<dim3(D / 64, L / 32, 1), 256, 0, stream>>>(
        Wbf, WtT, nullptr, bt, nullptr, nullptr, nullptr, nullptr, nullptr, out, Qb, D);
}